// Round 1
// baseline (238.493 us; speedup 1.0000x reference)
//
#include <hip/hip_runtime.h>
#include <hip/hip_bf16.h>

// SelectiveDense: out[b,g,u] = relu(sum_k x[b, idx[g,k]] * kern[g,k,u] + bias[u])
// B=8192 D=4096 G=256 K=32 U=64. f32 in/out, bf16 MFMA compute.

#define B_ 8192
#define D_ 4096
#define G_ 256
#define K_ 32
#define U_ 64

typedef short v8s __attribute__((ext_vector_type(8)));     // 8 bf16 (4 VGPRs) MFMA A/B frag
typedef float f32x4 __attribute__((ext_vector_type(4)));   // MFMA C/D frag

__device__ __forceinline__ unsigned short f2bf(float f) {
    unsigned int u = __float_as_uint(f);
    u = (u + 0x7FFFu + ((u >> 16) & 1u)) >> 16;   // round-to-nearest-even
    return (unsigned short)u;
}

// Pre-pass: kernels f32 [G][K][U] -> bf16 B-fragment layout [G][4 utiles][64 lanes][8]
// B frag for mfma_f32_16x16x32_bf16: lane l holds B[k=(l>>4)*8+j][col=l&15] (col = u within tile)
__global__ void prep_kb(const float* __restrict__ kern, unsigned short* __restrict__ kb) {
    int tid = blockIdx.x * blockDim.x + threadIdx.x;   // over G*K*U
    if (tid >= G_ * K_ * U_) return;
    int u = tid & (U_ - 1);
    int k = (tid >> 6) & (K_ - 1);
    int g = tid >> 11;
    int t = u >> 4;                       // u-tile 0..3
    int lane = ((k >> 3) << 4) | (u & 15);
    int j = k & 7;
    kb[((((g << 2) + t) << 6 | lane) << 3) | j] = f2bf(kern[tid]);
}

#define XS 4104   // LDS row stride in ushorts: 8208B, 16B-aligned rows, bank shift 4/row

__global__ void __launch_bounds__(256) sdense(
        const float* __restrict__ x, const unsigned short* __restrict__ kb,
        const float* __restrict__ bias, const int* __restrict__ idx,
        float* __restrict__ out) {
    extern __shared__ unsigned short lx[];   // [16][XS] bf16 x rows
    const int tid = threadIdx.x;
    const int b0 = blockIdx.x << 4;

    // ---- stage 16 rows of x (f32 -> bf16), coalesced, x read exactly once ----
    {
        const int row = tid >> 4;            // 0..15
        const int l16 = tid & 15;
        const float* xr = x + (size_t)(b0 + row) * D_;
        unsigned short* lr = lx + row * XS;
        #pragma unroll 4
        for (int i = 0; i < 32; ++i) {
            int col = (i << 7) + (l16 << 3);  // 8 floats per thread per iter
            float4 v0 = *(const float4*)(xr + col);
            float4 v1 = *(const float4*)(xr + col + 4);
            union { unsigned short u[8]; v8s v; } st;
            st.u[0] = f2bf(v0.x); st.u[1] = f2bf(v0.y);
            st.u[2] = f2bf(v0.z); st.u[3] = f2bf(v0.w);
            st.u[4] = f2bf(v1.x); st.u[5] = f2bf(v1.y);
            st.u[6] = f2bf(v1.z); st.u[7] = f2bf(v1.w);
            *(v8s*)(lr + col) = st.v;         // 16B ds_write, aligned
        }
    }
    __syncthreads();

    // ---- per-wave: 64 g's each; MFMA 16x16x32 per (g, utile) ----
    const int lane = tid & 63;
    const int w = tid >> 6;               // wave 0..3
    const int grp = lane >> 4;            // 0..3
    const int l15 = lane & 15;
    const int rowb = l15 * XS;            // A-operand row (M index) base in LDS
    const int kk0 = grp << 3;             // this lane-group's k range start

    float bias_v[4];
    #pragma unroll
    for (int t = 0; t < 4; ++t) bias_v[t] = bias[(t << 4) + l15];

    const v8s* kbv = (const v8s*)kb;

    for (int gi = 0; gi < 64; ++gi) {
        const int g = (w << 6) + gi;
        const int4* ip = (const int4*)(idx + (g << 5) + kk0);
        int4 ia = ip[0], ib = ip[1];

        union { unsigned short u[8]; v8s v; } A;   // A[l&15][(l>>4)*8 + j]
        A.u[0] = lx[rowb + ia.x]; A.u[1] = lx[rowb + ia.y];
        A.u[2] = lx[rowb + ia.z]; A.u[3] = lx[rowb + ia.w];
        A.u[4] = lx[rowb + ib.x]; A.u[5] = lx[rowb + ib.y];
        A.u[6] = lx[rowb + ib.z]; A.u[7] = lx[rowb + ib.w];

        const v8s* kg = kbv + ((g << 2) << 6) + lane;
        f32x4 acc[4];
        #pragma unroll
        for (int t = 0; t < 4; ++t) {
            v8s Bf = kg[t << 6];
            f32x4 z = {0.f, 0.f, 0.f, 0.f};
            acc[t] = __builtin_amdgcn_mfma_f32_16x16x32_bf16(A.v, Bf, z, 0, 0, 0);
        }

        // D layout: row=(lane>>4)*4+r (b), col=lane&15 (u within tile)
        float* ob = out + ((size_t)(b0 + (grp << 2)) * G_ + g) * U_ + l15;
        #pragma unroll
        for (int t = 0; t < 4; ++t) {
            #pragma unroll
            for (int r = 0; r < 4; ++r) {
                float v = acc[t][r] + bias_v[t];
                v = v > 0.f ? v : 0.f;
                ob[(size_t)r * (G_ * U_) + (t << 4)] = v;
            }
        }
    }
}

extern "C" void kernel_launch(void* const* d_in, const int* in_sizes, int n_in,
                              void* d_out, int out_size, void* d_ws, size_t ws_size,
                              hipStream_t stream) {
    const float* x    = (const float*)d_in[0];
    const float* kern = (const float*)d_in[1];
    const float* bias = (const float*)d_in[2];
    const int*   idx  = (const int*)d_in[3];
    float* out = (float*)d_out;
    unsigned short* kb = (unsigned short*)d_ws;   // 1 MiB bf16 kernel frags

    prep_kb<<<(G_ * K_ * U_ + 255) / 256, 256, 0, stream>>>(kern, kb);
    sdense<<<B_ / 16, 256, 16 * XS * sizeof(unsigned short), stream>>>(x, kb, bias, idx, out);
}